// Round 14
// baseline (198.163 us; speedup 1.0000x reference)
//
#include <hip/hip_runtime.h>
#include <math.h>

#define S_LEN 2048
#define DHEAD 128
#define NHEAD 16
#define QBLK  256                      // 4 waves x 64 q-rows (four 16-row M-tiles)
#define KVBLK 64
#define ATT_SCALE 0.08838834764831845f // 1/sqrt(128)
#define LOG2E 1.4426950408889634f
#define SHIFT2 11.5f                   // fixed softmax shift in log2 units

#define KP 136                         // K tile pitch (bf16 elems)
#define VP 72                          // V^T tile pitch

typedef __attribute__((ext_vector_type(4))) float f32x4;
typedef __attribute__((ext_vector_type(8))) short s16x8;
typedef __attribute__((ext_vector_type(2))) int   i32x2;

// RNE f32 pair -> packed bf16 dword (T12 recipe; no builtin on gfx950)
__device__ __forceinline__ int pk2(float lo, float hi) {
  int d;
  asm("v_cvt_pk_bf16_f32 %0, %1, %2" : "=v"(d) : "v"(lo), "v"(hi));
  return d;
}

// LDS-only barrier: global prefetch loads stay in flight across it.
#define BARRIER() do {                                   \
    asm volatile("s_waitcnt lgkmcnt(0)" ::: "memory");   \
    __builtin_amdgcn_s_barrier();                        \
  } while (0)

// r14 rationale: r11-r13 counters prove LDS-read-volume-bound (reads = 32KB x
// n_waves per tile, ~65% of wall; 3 schedule attempts null). Only cut: more
// q-rows per wave. 64 q/wave needs ~400 unified regs -> 1 wave/SIMD
// (launch_bounds(256,1) -> 512-reg budget). 4 waves x 64q = same 256-row tile,
// HALF the LDS reads. All latency hiding is now single-wave ILP.
// pi(j) kv-slot permutation as r7: applied to V^T staging slots AND pa pack
// order -> cancels in PV dot product; P stays fully in registers.

__global__ __launch_bounds__(256, 1)
void alibi_attn_fwd(const float* __restrict__ Qg, const float* __restrict__ Kg,
                    const float* __restrict__ Vg, float* __restrict__ Og)
{
  __shared__ __align__(16) short kt[2][KVBLK * KP];   // 34.8 KB
  __shared__ __align__(16) short vt[2][DHEAD * VP];   // 36.9 KB

  const int tid  = threadIdx.x;
  const int lane = tid & 63;
  const int w    = tid >> 6;      // wave 0..3, owns 64 q-rows per phase
  const int l16  = lane & 15;
  const int lg   = lane >> 4;     // 0..3

  // n = p*64 + bh: XCD = n&7 = bh&7 (head-local L2). p in 0..3.
  const int n    = blockIdx.x;
  const int bh   = n & 63;
  const int p    = n >> 6;
  const int head = bh & (NHEAD - 1);

  const size_t base = (size_t)bh * S_LEN * DHEAD;
  const float* Q = Qg + base;
  const float* K = Kg + base;
  const float* V = Vg + base;
  float*       O = Og + base;

  const float slope2 = exp2f(-0.5f * (float)(head + 1)) * LOG2E;
  float cn16[4], rsv[4];
  #pragma unroll
  for (int x = 0; x < 4; ++x) { cn16[x] = (float)(16 * x) * slope2; rsv[x] = (float)x * slope2; }

  s16x8 ones;
  #pragma unroll
  for (int jj = 0; jj < 8; ++jj) ones[jj] = (short)0x3f80;  // bf16 1.0

  const f32x4 zero4 = {0.f, 0.f, 0.f, 0.f};

  const int qt0 = 7 - p, qt1 = p;
  const int qb0 = qt0 * QBLK, qb1 = qt1 * QBLK;
  const int n0  = 4 * (qt0 + 1);
  const int NT  = n0 + 4 * (qt1 + 1);   // 36 for every block

  // ---- staging maps (256 threads, one tile shared by all 4 waves) ----
  // K: row kr (0..63), d = kd0..kd0+31 (8 f32x4 loads, 4 b128 writes)
  const int kr  = tid >> 2;
  const int kd0 = 32 * (tid & 3);
  // V: rows Rv..Rv+3, d = d0v..d0v+7 -> 8 i32x2 writes at pi slots vslotb..+3
  const int grp = tid & 15, vnt = grp >> 2, vg = grp & 3;
  const int Rv  = 16 * vnt + 4 * vg;
  const int d0v = 8 * (tid >> 4);
  const int vslotb = 32 * (vnt >> 1) + 8 * vg + 4 * (vnt & 1);

  f32x4 ka[8], va[8];   // prefetch regs: one tile in flight (64 VGPRs)

#define LOAD_TILE(KV0) do {                                            \
    const float* kp_ = K + (size_t)((KV0) + kr) * DHEAD + kd0;         \
    ka[0] = *(const f32x4*)(kp_);      ka[1] = *(const f32x4*)(kp_ + 4);   \
    ka[2] = *(const f32x4*)(kp_ + 8);  ka[3] = *(const f32x4*)(kp_ + 12);  \
    ka[4] = *(const f32x4*)(kp_ + 16); ka[5] = *(const f32x4*)(kp_ + 20);  \
    ka[6] = *(const f32x4*)(kp_ + 24); ka[7] = *(const f32x4*)(kp_ + 28);  \
    const float* vp_ = V + (size_t)((KV0) + Rv) * DHEAD + d0v;         \
    va[0] = *(const f32x4*)(vp_);             va[1] = *(const f32x4*)(vp_ + 4);           \
    va[2] = *(const f32x4*)(vp_ + DHEAD);     va[3] = *(const f32x4*)(vp_ + DHEAD + 4);   \
    va[4] = *(const f32x4*)(vp_ + 2*DHEAD);   va[5] = *(const f32x4*)(vp_ + 2*DHEAD + 4); \
    va[6] = *(const f32x4*)(vp_ + 3*DHEAD);   va[7] = *(const f32x4*)(vp_ + 3*DHEAD + 4); \
  } while (0)

#define STORE_TILE(B) do {                                             \
    short* ktp = &kt[B][kr * KP + kd0];                                \
    _Pragma("unroll")                                                  \
    for (int h = 0; h < 4; ++h) {                                      \
      union { int d[4]; s16x8 v; } uu;                                 \
      uu.d[0] = pk2(ka[2*h][0],   ka[2*h][1]);                         \
      uu.d[1] = pk2(ka[2*h][2],   ka[2*h][3]);                         \
      uu.d[2] = pk2(ka[2*h+1][0], ka[2*h+1][1]);                       \
      uu.d[3] = pk2(ka[2*h+1][2], ka[2*h+1][3]);                       \
      *(s16x8*)(ktp + 8*h) = uu.v;                                     \
    }                                                                  \
    _Pragma("unroll")                                                  \
    for (int e = 0; e < 8; ++e) {                                      \
      i32x2 dvv;                                                       \
      dvv[0] = pk2(va[(e>>2)][e&3],     va[2+(e>>2)][e&3]);            \
      dvv[1] = pk2(va[4+(e>>2)][e&3],   va[6+(e>>2)][e&3]);            \
      *(i32x2*)&vt[B][(d0v + e) * VP + vslotb] = dvv;                  \
    }                                                                  \
  } while (0)

  // ---- per-phase state: 4 M-tiles per wave ----
  s16x8 qf[4][4];
  f32x4 oacc[4][8], lacc[4];
  int   iq0 = 0;
  int   qb  = qb0;

  auto init_phase = [&](int qbn) {
    qb  = qbn;
    iq0 = qbn + 64 * w + l16;
    #pragma unroll
    for (int m = 0; m < 4; ++m) {
      const float* qp = Q + (size_t)(qbn + 64*w + 16*m + l16) * DHEAD + 8*lg;
      #pragma unroll
      for (int c = 0; c < 4; ++c) {
        f32x4 a = *(const f32x4*)(qp + 32*c);
        f32x4 b = *(const f32x4*)(qp + 32*c + 4);
        const float sc = ATT_SCALE * LOG2E;
        union { int d[4]; s16x8 v; } uu;
        uu.d[0] = pk2(a[0]*sc, a[1]*sc); uu.d[1] = pk2(a[2]*sc, a[3]*sc);
        uu.d[2] = pk2(b[0]*sc, b[1]*sc); uu.d[3] = pk2(b[2]*sc, b[3]*sc);
        qf[m][c] = uu.v;
      }
      #pragma unroll
      for (int dt = 0; dt < 8; ++dt) oacc[m][dt] = zero4;
      lacc[m] = zero4;
    }
  };

  auto epilogue = [&](int qbn) {
    #pragma unroll
    for (int m = 0; m < 4; ++m) {
      #pragma unroll
      for (int r = 0; r < 4; ++r) {
        const float inv = 1.0f / lacc[m][r];
        float* op = O + (size_t)(qbn + 64*w + 16*m + 4*lg + r) * DHEAD + l16;
        #pragma unroll
        for (int dt = 0; dt < 8; ++dt) op[dt * 16] = oacc[m][dt][r] * inv;
      }
    }
  };

  init_phase(qb0);
  LOAD_TILE(0);
  STORE_TILE(0);
  LOAD_TILE(KVBLK);          // tile 1 (n0 >= 20, always in phase 0)
  __syncthreads();           // prologue: full sync once

  for (int s = 0; s < NT; ++s) {
    if (s == n0) { epilogue(qb0); init_phase(qb1); }
    const int cur = s & 1;
    if (s + 1 < NT) STORE_TILE((s + 1) & 1);   // other buffer
    if (s + 2 < NT) {
      const int s2 = s + 2;
      LOAD_TILE(((s2 < n0) ? s2 : s2 - n0) * KVBLK);
    }
    const int kv0 = ((s < n0) ? s : s - n0) * KVBLK;

    if (kv0 <= qb + 64 * w + 63) {
      const short* ktc = kt[cur];
      const short* vtc = vt[cur];

      // ---- QK^T swapped: sacc = K * Q^T; each kf feeds FOUR M-tiles ----
      f32x4 sacc[4][4];
      #pragma unroll
      for (int m = 0; m < 4; ++m)
        #pragma unroll
        for (int nt = 0; nt < 4; ++nt) sacc[m][nt] = zero4;
      #pragma unroll
      for (int c = 0; c < 4; ++c) {
        #pragma unroll
        for (int nt = 0; nt < 4; ++nt) {
          s16x8 kf = *(const s16x8*)&ktc[(nt*16 + l16) * KP + 32*c + 8*lg];
          #pragma unroll
          for (int m = 0; m < 4; ++m)
            sacc[m][nt] = __builtin_amdgcn_mfma_f32_16x16x32_bf16(kf, qf[m][c], sacc[m][nt], 0, 0, 0);
        }
      }

      // ---- softmax in-register: p = 2^(s + (j-i)*slope2 - SHIFT2) ----
      const bool needMask = (kv0 + KVBLK - 1 > qb + 64 * w);
      s16x8 pa[4][2];
      #pragma unroll
      for (int m = 0; m < 4; ++m) {
        const int dji = kv0 + 4*lg - (iq0 + 16*m);   // j - i at (nt=0, r=0)
        const float b0m = (float)dji * slope2 - SHIFT2;
        float pv[4][4];
        #pragma unroll
        for (int nt = 0; nt < 4; ++nt) {
          const float bmn = b0m + cn16[nt];
          #pragma unroll
          for (int r = 0; r < 4; ++r)
            pv[nt][r] = __builtin_amdgcn_exp2f(sacc[m][nt][r] + bmn + rsv[r]);
        }
        if (needMask) {
          #pragma unroll
          for (int nt = 0; nt < 4; ++nt)
            #pragma unroll
            for (int r = 0; r < 4; ++r)
              if (dji + 16*nt + r > 0) pv[nt][r] = 0.f;
        }
        #pragma unroll
        for (int c2 = 0; c2 < 2; ++c2) {
          union { int d[4]; s16x8 v; } uu;
          uu.d[0] = pk2(pv[2*c2][0],   pv[2*c2][1]);
          uu.d[1] = pk2(pv[2*c2][2],   pv[2*c2][3]);
          uu.d[2] = pk2(pv[2*c2+1][0], pv[2*c2+1][1]);
          uu.d[3] = pk2(pv[2*c2+1][2], pv[2*c2+1][3]);
          pa[m][c2] = uu.v;   // k-slots c2*32 + 8*lg .. +7 in pi space
        }
      }

      // ---- PV in pi space; each bv feeds FOUR M-tiles; row-sum via ones ----
      #pragma unroll
      for (int c2 = 0; c2 < 2; ++c2) {
        #pragma unroll
        for (int m = 0; m < 4; ++m)
          lacc[m] = __builtin_amdgcn_mfma_f32_16x16x32_bf16(pa[m][c2], ones, lacc[m], 0, 0, 0);
        #pragma unroll
        for (int dt = 0; dt < 8; ++dt) {
          s16x8 bv = *(const s16x8*)&vtc[(dt*16 + l16) * VP + c2*32 + 8*lg];
          #pragma unroll
          for (int m = 0; m < 4; ++m)
            oacc[m][dt] = __builtin_amdgcn_mfma_f32_16x16x32_bf16(pa[m][c2], bv, oacc[m][dt], 0, 0, 0);
        }
      }
    }

    BARRIER();   // lgkm-only: prefetch loads stay in flight across it
  }
  epilogue(qb1);
}

extern "C" void kernel_launch(void* const* d_in, const int* in_sizes, int n_in,
                              void* d_out, int out_size, void* d_ws, size_t ws_size,
                              hipStream_t stream) {
  (void)in_sizes; (void)n_in; (void)out_size; (void)d_ws; (void)ws_size;
  const float* q = (const float*)d_in[0];
  const float* k = (const float*)d_in[1];
  const float* v = (const float*)d_in[2];
  float* o = (float*)d_out;
  dim3 grid(256);    // 64 heads x 4 uniform q-tile pairs; 1 block/CU
  dim3 block(256);   // 4 waves, 1 wave/SIMD, 512-reg budget
  alibi_attn_fwd<<<grid, block, 0, stream>>>(q, k, v, o);
}

// Round 15
// 108.742 us; speedup vs baseline: 1.8223x; 1.8223x over previous
//
#include <hip/hip_runtime.h>
#include <math.h>

#define S_LEN 2048
#define DHEAD 128
#define NHEAD 16
#define QBLK  256                      // 8 waves x 32 q-rows (two 16-row M-tiles)
#define KVBLK 64
#define ATT_SCALE 0.08838834764831845f // 1/sqrt(128)
#define LOG2E 1.4426950408889634f
#define SHIFT2 11.5f                   // fixed softmax shift in log2 units

#define KP 136                         // K tile pitch (bf16 elems)
#define VP 72                          // V^T tile pitch

typedef __attribute__((ext_vector_type(4))) float f32x4;
typedef __attribute__((ext_vector_type(8))) short s16x8;
typedef __attribute__((ext_vector_type(2))) int   i32x2;

// RNE f32 pair -> packed bf16 dword (T12 recipe; no builtin on gfx950)
__device__ __forceinline__ int pk2(float lo, float hi) {
  int d;
  asm("v_cvt_pk_bf16_f32 %0, %1, %2" : "=v"(d) : "v"(lo), "v"(hi));
  return d;
}

// r15: wave ROLE-SPLIT (T5's mechanism). r11-r13 showed the 8-wave lockstep
// schedule time-slices the pipes (LDS 3084 + MFMA 1320 + VALU 1100 cy/tile
// ~= serialized = 7070 cy wall). Each SIMD hosts waves w and w+4; giving them
// OPPOSITE phase orders makes pipe usage heterogeneous at every instant:
//   A (w<4):  QK(s) -> sm(s) -> PV(s)
//   B (w>=4): PV(s-1) [carried P] -> QK(s) -> sm(s) [keep P]
// Race-freedom, one barrier/tile: K double-buffered (read K[s&1], write
// K[(s+1)&1]); V TRIPLE-buffered (A reads V[s%3], B reads V[(s-1)%3], store
// writes V[(s+1)%3] -- all distinct mod 3). LDS 90KB, 1 block/CU.
// pi(j) kv-slot permutation as before: P stays fully in registers, 0 shuffles.

__global__ __launch_bounds__(512, 2)
void alibi_attn_fwd(const float* __restrict__ Qg, const float* __restrict__ Kg,
                    const float* __restrict__ Vg, float* __restrict__ Og)
{
  __shared__ __align__(16) short kt[2][KVBLK * KP];   // 34.8 KB
  __shared__ __align__(16) short vt[3][DHEAD * VP];   // 55.3 KB

  const int tid  = threadIdx.x;
  const int lane = tid & 63;
  const int w    = tid >> 6;      // wave 0..7, owns 32 q-rows per phase
  const int l16  = lane & 15;
  const int lg   = lane >> 4;     // 0..3
  const bool isB = (w >= 4);      // SIMD = w&3 -> each SIMD gets one A + one B

  // n = p*64 + bh: XCD = n&7 = bh&7 (head-local L2). p in 0..3.
  const int n    = blockIdx.x;
  const int bh   = n & 63;
  const int p    = n >> 6;
  const int head = bh & (NHEAD - 1);

  const size_t base = (size_t)bh * S_LEN * DHEAD;
  const float* Q = Qg + base;
  const float* K = Kg + base;
  const float* V = Vg + base;
  float*       O = Og + base;

  const float slope2 = exp2f(-0.5f * (float)(head + 1)) * LOG2E;
  float cn16[4], rsv[4];
  #pragma unroll
  for (int x = 0; x < 4; ++x) { cn16[x] = (float)(16 * x) * slope2; rsv[x] = (float)x * slope2; }

  s16x8 ones;
  #pragma unroll
  for (int jj = 0; jj < 8; ++jj) ones[jj] = (short)0x3f80;  // bf16 1.0

  const f32x4 zero4 = {0.f, 0.f, 0.f, 0.f};

  const int qt0 = 7 - p, qt1 = p;
  const int qb0 = qt0 * QBLK, qb1 = qt1 * QBLK;
  const int n0  = 4 * (qt0 + 1);
  const int NT  = n0 + 4 * (qt1 + 1);   // 36 for every block

  // ---- staging maps (512 threads, one tile shared by all 8 waves) ----
  const int kr  = tid >> 3;             // K row 0..63, d = d0k..d0k+15
  const int d0k = 16 * (tid & 7);
  const int grp = tid & 15, vnt = grp >> 2, vg = grp & 3;
  const int Rv  = 16 * vnt + 4 * vg;    // V rows Rv..Rv+3
  const int dv  = 4 * (tid >> 4);       // V d = dv..dv+3
  const int vslotb = 32 * (vnt >> 1) + 8 * vg + 4 * (vnt & 1);  // pi slot base

  f32x4 ka[4], va[4];   // prefetch regs: one tile in flight (32 VGPRs)

#define LOAD_TILE(KV0) do {                                            \
    const float* kp_ = K + (size_t)((KV0) + kr) * DHEAD + d0k;         \
    ka[0] = *(const f32x4*)(kp_);      ka[1] = *(const f32x4*)(kp_ + 4);  \
    ka[2] = *(const f32x4*)(kp_ + 8);  ka[3] = *(const f32x4*)(kp_ + 12); \
    const float* vp_ = V + (size_t)((KV0) + Rv) * DHEAD + dv;          \
    va[0] = *(const f32x4*)(vp_);                                      \
    va[1] = *(const f32x4*)(vp_ + DHEAD);                              \
    va[2] = *(const f32x4*)(vp_ + 2*DHEAD);                            \
    va[3] = *(const f32x4*)(vp_ + 3*DHEAD);                            \
  } while (0)

#define STORE_TILE(BK, BV) do {                                        \
    short* ktp = &kt[BK][kr * KP + d0k];                               \
    union { int d[4]; s16x8 v; } u0, u1;                               \
    u0.d[0] = pk2(ka[0][0], ka[0][1]); u0.d[1] = pk2(ka[0][2], ka[0][3]); \
    u0.d[2] = pk2(ka[1][0], ka[1][1]); u0.d[3] = pk2(ka[1][2], ka[1][3]); \
    u1.d[0] = pk2(ka[2][0], ka[2][1]); u1.d[1] = pk2(ka[2][2], ka[2][3]); \
    u1.d[2] = pk2(ka[3][0], ka[3][1]); u1.d[3] = pk2(ka[3][2], ka[3][3]); \
    *(s16x8*)(ktp)     = u0.v;                                         \
    *(s16x8*)(ktp + 8) = u1.v;                                         \
    _Pragma("unroll")                                                  \
    for (int e = 0; e < 4; ++e) {                                      \
      i32x2 dvv;                                                       \
      dvv[0] = pk2(va[0][e], va[1][e]);                                \
      dvv[1] = pk2(va[2][e], va[3][e]);                                \
      *(i32x2*)&vt[BV][(dv + e) * VP + vslotb] = dvv;                  \
    }                                                                  \
  } while (0)

  // ---- per-phase state ----
  s16x8 qf[2][4];
  f32x4 oacc[2][8], lacc[2];
  int   iq0 = 0;
  int   qb  = qb0;

  auto init_phase = [&](int qbn) {
    qb  = qbn;
    iq0 = qbn + 32 * w + l16;
    #pragma unroll
    for (int m = 0; m < 2; ++m) {
      const float* qp = Q + (size_t)(qbn + 32*w + 16*m + l16) * DHEAD + 8*lg;
      #pragma unroll
      for (int c = 0; c < 4; ++c) {
        f32x4 a = *(const f32x4*)(qp + 32*c);
        f32x4 b = *(const f32x4*)(qp + 32*c + 4);
        const float sc = ATT_SCALE * LOG2E;
        union { int d[4]; s16x8 v; } uu;
        uu.d[0] = pk2(a[0]*sc, a[1]*sc); uu.d[1] = pk2(a[2]*sc, a[3]*sc);
        uu.d[2] = pk2(b[0]*sc, b[1]*sc); uu.d[3] = pk2(b[2]*sc, b[3]*sc);
        qf[m][c] = uu.v;
      }
      #pragma unroll
      for (int dt = 0; dt < 8; ++dt) oacc[m][dt] = zero4;
      lacc[m] = zero4;
    }
  };

  auto epilogue = [&](int qbn) {
    #pragma unroll
    for (int m = 0; m < 2; ++m) {
      #pragma unroll
      for (int r = 0; r < 4; ++r) {
        const float inv = 1.0f / lacc[m][r];
        float* op = O + (size_t)(qbn + 32*w + 16*m + 4*lg + r) * DHEAD + l16;
        #pragma unroll
        for (int dt = 0; dt < 8; ++dt) op[dt * 16] = oacc[m][dt][r] * inv;
      }
    }
  };

  // ---- QK^T + softmax -> packed P fragments (pi slot order) ----
  auto qk_sm = [&](const short* ktc, int kv0, s16x8 (&paO)[2][2]) {
    f32x4 sacc[2][4];
    #pragma unroll
    for (int nt = 0; nt < 4; ++nt) { sacc[0][nt] = zero4; sacc[1][nt] = zero4; }
    __builtin_amdgcn_s_setprio(1);
    #pragma unroll
    for (int c = 0; c < 4; ++c) {
      #pragma unroll
      for (int nt = 0; nt < 4; ++nt) {
        s16x8 kf = *(const s16x8*)&ktc[(nt*16 + l16) * KP + 32*c + 8*lg];
        sacc[0][nt] = __builtin_amdgcn_mfma_f32_16x16x32_bf16(kf, qf[0][c], sacc[0][nt], 0, 0, 0);
        sacc[1][nt] = __builtin_amdgcn_mfma_f32_16x16x32_bf16(kf, qf[1][c], sacc[1][nt], 0, 0, 0);
      }
    }
    __builtin_amdgcn_s_setprio(0);

    const bool needMask = (kv0 + KVBLK - 1 > qb + 32 * w);  // diagonal tiles only
    #pragma unroll
    for (int m = 0; m < 2; ++m) {
      const int dji = kv0 + 4*lg - (iq0 + 16*m);   // j - i at (nt=0, r=0)
      const float b0m = (float)dji * slope2 - SHIFT2;
      float pv[4][4];
      #pragma unroll
      for (int nt = 0; nt < 4; ++nt) {
        const float bmn = b0m + cn16[nt];
        #pragma unroll
        for (int r = 0; r < 4; ++r)
          pv[nt][r] = __builtin_amdgcn_exp2f(sacc[m][nt][r] + bmn + rsv[r]);
      }
      if (needMask) {
        #pragma unroll
        for (int nt = 0; nt < 4; ++nt)
          #pragma unroll
          for (int r = 0; r < 4; ++r)
            if (dji + 16*nt + r > 0) pv[nt][r] = 0.f;
      }
      #pragma unroll
      for (int c2 = 0; c2 < 2; ++c2) {
        union { int d[4]; s16x8 v; } uu;
        uu.d[0] = pk2(pv[2*c2][0],   pv[2*c2][1]);
        uu.d[1] = pk2(pv[2*c2][2],   pv[2*c2][3]);
        uu.d[2] = pk2(pv[2*c2+1][0], pv[2*c2+1][1]);
        uu.d[3] = pk2(pv[2*c2+1][2], pv[2*c2+1][3]);
        paO[m][c2] = uu.v;   // k-slots c2*32 + 8*lg .. +7 in pi space
      }
    }
  };

  // ---- PV in pi space; row-sum via ones-MFMA ----
  auto pv_block = [&](const short* vtc, const s16x8 (&paI)[2][2]) {
    __builtin_amdgcn_s_setprio(1);
    #pragma unroll
    for (int c2 = 0; c2 < 2; ++c2) {
      lacc[0] = __builtin_amdgcn_mfma_f32_16x16x32_bf16(paI[0][c2], ones, lacc[0], 0, 0, 0);
      lacc[1] = __builtin_amdgcn_mfma_f32_16x16x32_bf16(paI[1][c2], ones, lacc[1], 0, 0, 0);
      #pragma unroll
      for (int dt = 0; dt < 8; ++dt) {
        s16x8 bv = *(const s16x8*)&vtc[(dt*16 + l16) * VP + c2*32 + 8*lg];
        oacc[0][dt] = __builtin_amdgcn_mfma_f32_16x16x32_bf16(paI[0][c2], bv, oacc[0][dt], 0, 0, 0);
        oacc[1][dt] = __builtin_amdgcn_mfma_f32_16x16x32_bf16(paI[1][c2], bv, oacc[1][dt], 0, 0, 0);
      }
    }
    __builtin_amdgcn_s_setprio(0);
  };

  s16x8 pa[2][2];        // A: region-local; B: carried across the barrier
  bool  pend = false;    // B only: P from tile s-1 awaiting PV

  init_phase(qb0);
  LOAD_TILE(0);
  STORE_TILE(0, 0);
  LOAD_TILE(KVBLK);          // tile 1 (n0 >= 20, always in phase 0)
  __syncthreads();

  for (int s = 0; s < NT; ++s) {
    if (s == n0) {           // phase boundary: B drains pending PV first
      if (isB && pend) pv_block(vt[(n0 + 2) % 3], pa);   // tile n0-1
      epilogue(qb0);
      init_phase(qb1);
      pend = false;
    }
    if (s + 1 < NT) STORE_TILE((s + 1) & 1, (s + 1) % 3);
    if (s + 2 < NT) {
      const int s2 = s + 2;
      LOAD_TILE(((s2 < n0) ? s2 : s2 - n0) * KVBLK);
    }
    const int kv0 = ((s < n0) ? s : s - n0) * KVBLK;
    const bool active = (kv0 <= qb + 32 * w + 31);

    if (!isB) {
      // A: QK(s) -> sm(s) -> PV(s)
      if (active) {
        qk_sm(kt[s & 1], kv0, pa);
        pv_block(vt[s % 3], pa);
      }
    } else {
      // B: PV(s-1) -> QK(s) -> sm(s), keep P for next region
      if (pend) pv_block(vt[(s + 2) % 3], pa);           // (s-1) mod 3
      if (active) qk_sm(kt[s & 1], kv0, pa);
      pend = active;
    }

    __syncthreads();
  }
  if (isB && pend) pv_block(vt[(NT + 2) % 3], pa);       // drain last tile
  epilogue(qb1);
}

extern "C" void kernel_launch(void* const* d_in, const int* in_sizes, int n_in,
                              void* d_out, int out_size, void* d_ws, size_t ws_size,
                              hipStream_t stream) {
  (void)in_sizes; (void)n_in; (void)out_size; (void)d_ws; (void)ws_size;
  const float* q = (const float*)d_in[0];
  const float* k = (const float*)d_in[1];
  const float* v = (const float*)d_in[2];
  float* o = (float*)d_out;
  dim3 grid(256);    // 64 heads x 4 uniform q-tile pairs; exactly 1 block/CU
  dim3 block(512);
  alibi_attn_fwd<<<grid, block, 0, stream>>>(q, k, v, o);
}